// Round 4
// baseline (292.624 us; speedup 1.0000x reference)
//
#include <hip/hip_runtime.h>

typedef __bf16 bf16x8 __attribute__((ext_vector_type(8)));
typedef float f32x4 __attribute__((ext_vector_type(4)));

#define N_TOK 8192
#define DMODEL 1024
#define NEXP 64
#define ESIZE 128
#define WL_MAX 1088   // sum ceil(ck/32) <= 32768/32 + 64 = 1088 (divisible by 8)

__device__ __forceinline__ unsigned short f2bf(float f) {
  unsigned int u = __builtin_bit_cast(unsigned int, f);
  u += 0x7FFFu + ((u >> 16) & 1u);
  return (unsigned short)(u >> 16);
}

__device__ __forceinline__ float b2f(unsigned short u) {
  unsigned int v = ((unsigned int)u) << 16;
  return __builtin_bit_cast(float, v);
}

// K0: expert_sel [64][1024] -> selT [1024][64] fp32
__global__ void k_selT(const float* __restrict__ in, float* __restrict__ outT) {
  int id = blockIdx.x * 256 + threadIdx.x;
  int e = id & 63, j = id >> 6;
  outT[id] = in[e * DMODEL + j];
}

// K1: x fp32 -> bf16
__global__ void k_castx(const float* __restrict__ in, unsigned short* __restrict__ out) {
  size_t i = (size_t)(blockIdx.x * 256 + threadIdx.x) * 8;
  float4 a = *reinterpret_cast<const float4*>(in + i);
  float4 b = *reinterpret_cast<const float4*>(in + i + 4);
  uint4 o;
  o.x = f2bf(a.x) | ((unsigned)f2bf(a.y) << 16);
  o.y = f2bf(a.z) | ((unsigned)f2bf(a.w) << 16);
  o.z = f2bf(b.x) | ((unsigned)f2bf(b.y) << 16);
  o.w = f2bf(b.z) | ((unsigned)f2bf(b.w) << 16);
  *reinterpret_cast<uint4*>(out + i) = o;
}

// K2: per-expert transpose+cast: in [B][R][C] f32 -> out [B][C][R] bf16
__global__ void k_transpose(const float* __restrict__ in, unsigned short* __restrict__ out,
                            int R, int C) {
  __shared__ float t[32][33];
  int b = blockIdx.y;
  int tilesC = C >> 5;
  int tr = blockIdx.x / tilesC, tc = blockIdx.x % tilesC;
  int lr = threadIdx.x >> 5, lc = threadIdx.x & 31;
  const float* ip = in + (size_t)b * R * C;
  unsigned short* op = out + (size_t)b * R * C;
#pragma unroll
  for (int p = 0; p < 4; ++p)
    t[p * 8 + lr][lc] = ip[(size_t)(tr * 32 + p * 8 + lr) * C + tc * 32 + lc];
  __syncthreads();
#pragma unroll
  for (int p = 0; p < 4; ++p)
    op[(size_t)(tc * 32 + p * 8 + lr) * R + tr * 32 + lc] = f2bf(t[lc][p * 8 + lr]);
}

// K3: router — LDS-tiled fp64-accum GEMM (rank fidelity) + per-token top-4.
__global__ __launch_bounds__(256) void k_router(const float* __restrict__ x,
                                                const float* __restrict__ selT,
                                                int4* __restrict__ idx4,
                                                float4* __restrict__ g4) {
  int tid = threadIdx.x;
  int tok0 = blockIdx.x * 32;
  int ty = tid >> 4, tx = tid & 15;
  __shared__ float lx[32][34];
  __shared__ float ls[32][64];
  __shared__ double lg[32][65];

  int tokr = tid >> 3, dseg = (tid & 7) * 4;
  int srow = tid >> 3, scol = (tid & 7) * 8;

  double acc[2][4];
#pragma unroll
  for (int r = 0; r < 2; ++r)
#pragma unroll
    for (int c = 0; c < 4; ++c) acc[r][c] = 0.0;

  for (int cc = 0; cc < DMODEL; cc += 32) {
    float4 xv = *reinterpret_cast<const float4*>(&x[(size_t)(tok0 + tokr) * DMODEL + cc + dseg]);
    lx[dseg + 0][tokr] = xv.x;
    lx[dseg + 1][tokr] = xv.y;
    lx[dseg + 2][tokr] = xv.z;
    lx[dseg + 3][tokr] = xv.w;
    *reinterpret_cast<float4*>(&ls[srow][scol]) =
        *reinterpret_cast<const float4*>(&selT[(size_t)(cc + srow) * 64 + scol]);
    *reinterpret_cast<float4*>(&ls[srow][scol + 4]) =
        *reinterpret_cast<const float4*>(&selT[(size_t)(cc + srow) * 64 + scol + 4]);
    __syncthreads();
#pragma unroll
    for (int j = 0; j < 32; ++j) {
      float2 xj = *reinterpret_cast<const float2*>(&lx[j][ty * 2]);
      float4 sj = *reinterpret_cast<const float4*>(&ls[j][tx * 4]);
      double x0 = (double)xj.x, x1 = (double)xj.y;
      double s0 = (double)sj.x, s1 = (double)sj.y, s2 = (double)sj.z, s3 = (double)sj.w;
      acc[0][0] += x0 * s0; acc[0][1] += x0 * s1; acc[0][2] += x0 * s2; acc[0][3] += x0 * s3;
      acc[1][0] += x1 * s0; acc[1][1] += x1 * s1; acc[1][2] += x1 * s2; acc[1][3] += x1 * s3;
    }
    __syncthreads();
  }

#pragma unroll
  for (int r = 0; r < 2; ++r)
#pragma unroll
    for (int c = 0; c < 4; ++c) lg[ty * 2 + r][tx * 4 + c] = acc[r][c];
  __syncthreads();

  if (tid < 32) {
    double bv0 = -1.0e300, bv1 = -1.0e300, bv2 = -1.0e300, bv3 = -1.0e300;
    int bi0 = 0, bi1 = 0, bi2 = 0, bi3 = 0;
    for (int e = 0; e < 64; ++e) {
      double v = lg[tid][e];
      if (v > bv3) {
        if (v > bv0) {
          bv3 = bv2; bi3 = bi2; bv2 = bv1; bi2 = bi1; bv1 = bv0; bi1 = bi0; bv0 = v; bi0 = e;
        } else if (v > bv1) {
          bv3 = bv2; bi3 = bi2; bv2 = bv1; bi2 = bi1; bv1 = v; bi1 = e;
        } else if (v > bv2) {
          bv3 = bv2; bi3 = bi2; bv2 = v; bi2 = e;
        } else {
          bv3 = v; bi3 = e;
        }
      }
    }
    idx4[tok0 + tid] = make_int4(bi0, bi1, bi2, bi3);
    float4 g;
    g.x = 1.0f / (1.0f + __expf(-(float)bv0));
    g.y = 1.0f / (1.0f + __expf(-(float)bv1));
    g.z = 1.0f / (1.0f + __expf(-(float)bv2));
    g.w = 1.0f / (1.0f + __expf(-(float)bv3));
    g4[tok0 + tid] = g;
  }
}

// K4: two-level atomic bucketize. Slot order within a bucket is non-deterministic,
// but each part-row (head,token) is written exactly once -> output invariant.
__global__ __launch_bounds__(256) void k_bucket(const int4* __restrict__ idx4,
                                                const float4* __restrict__ g4,
                                                int* __restrict__ btok,
                                                float* __restrict__ bgate,
                                                int* __restrict__ cnt) {
  __shared__ int lcnt[64];
  __shared__ int lbase[64];
  int tid = threadIdx.x;
  if (tid < 64) lcnt[tid] = 0;
  __syncthreads();
  int n = blockIdx.x * 256 + tid;
  int4 I = idx4[n];
  float4 G = g4[n];
  int e[4] = {I.x, I.y, I.z, I.w};
  float g[4] = {G.x, G.y, G.z, G.w};
  int pos[4];
#pragma unroll
  for (int h = 0; h < 4; ++h) pos[h] = atomicAdd(&lcnt[e[h]], 1);
  __syncthreads();
  if (tid < 64 && lcnt[tid] > 0) lbase[tid] = atomicAdd(&cnt[tid], lcnt[tid]);
  __syncthreads();
#pragma unroll
  for (int h = 0; h < 4; ++h) {
    int slot = lbase[e[h]] + pos[h];
    btok[e[h] * N_TOK + slot] = h * N_TOK + n;
    bgate[e[h] * N_TOK + slot] = g[h];
  }
}

// K5: compact worklist of (expert, tile32) pairs. 1 block, 64 threads.
__global__ void k_worklist(const int* __restrict__ cnt, int* __restrict__ wl) {
  int lane = threadIdx.x;
  int nt = (cnt[lane] + 31) >> 5;
  int off = nt;
  for (int d = 1; d < 64; d <<= 1) {
    int o = __shfl_up(off, d);
    if (lane >= d) off += o;
  }
  int total = __shfl(off, 63);
  off -= nt;
  for (int t = 0; t < nt; ++t) wl[off + t] = (lane << 8) | t;
  for (int i = total + lane; i < WL_MAX; i += 64) wl[i] = -1;
}

// K6: fused per-(expert,tile32), 4 waves (2x2), explicit depth-1 register
// double-buffering on both GEMM k-loops. Direct-global MFMA fragments.
__global__ __launch_bounds__(256, 2) void k_expert(
    const unsigned short* __restrict__ xbf, const unsigned short* __restrict__ kbf,
    const unsigned short* __restrict__ vbf, const int* __restrict__ wl,
    const int* __restrict__ btok, const float* __restrict__ bgate,
    const int* __restrict__ cnt, unsigned short* __restrict__ part) {
  int wid = (blockIdx.x & 7) * (WL_MAX / 8) + (blockIdx.x >> 3);
  int wle = wl[wid];
  if (wle < 0) return;
  int k = wle >> 8, tile = wle & 255;
  int ck = cnt[k];
  int tid = threadIdx.x, lane = tid & 63;
  int wv = tid >> 6, wr = wv >> 1, wc = wv & 1;
  int col = lane & 15, grp = lane >> 4;

  __shared__ unsigned short lS[32][136];
  __shared__ int sRow[32];
  __shared__ float sGate[32];

  if (tid < 32) {
    int i = tile * 32 + tid;
    bool valid = i < ck;
    sRow[tid] = valid ? btok[k * N_TOK + i] : 4 * N_TOK + wid;  // per-block dump row
    sGate[tid] = valid ? bgate[k * N_TOK + i] : 0.0f;
  }
  __syncthreads();

  const unsigned short* kb = kbf + (size_t)k * (ESIZE * DMODEL);
  const unsigned short* vb = vbf + (size_t)k * (DMODEL * ESIZE);

  // ---- GEMM1: wave (wr,wc) -> tokens [wr*16,+16), e-cols [wc*64,+64)
  const unsigned short* aP =
      xbf + (size_t)(sRow[wr * 16 + col] & (N_TOK - 1)) * DMODEL + grp * 8;
  const unsigned short* bP[4];
#pragma unroll
  for (int nf = 0; nf < 4; ++nf)
    bP[nf] = kb + (size_t)(wc * 64 + nf * 16 + col) * DMODEL + grp * 8;

  f32x4 acc[4] = {};
  bf16x8 aC = *reinterpret_cast<const bf16x8*>(aP);
  bf16x8 bC[4];
#pragma unroll
  for (int nf = 0; nf < 4; ++nf) bC[nf] = *reinterpret_cast<const bf16x8*>(bP[nf]);

#pragma unroll 2
  for (int kk = 0; kk < DMODEL; kk += 32) {
    int nk = (kk + 32) & (DMODEL - 1);  // wraps to 0 on last iter (harmless refetch)
    bf16x8 aN = *reinterpret_cast<const bf16x8*>(aP + nk);
    bf16x8 bN[4];
#pragma unroll
    for (int nf = 0; nf < 4; ++nf) bN[nf] = *reinterpret_cast<const bf16x8*>(bP[nf] + nk);
#pragma unroll
    for (int nf = 0; nf < 4; ++nf)
      acc[nf] = __builtin_amdgcn_mfma_f32_16x16x32_bf16(aC, bC[nf], acc[nf], 0, 0, 0);
    aC = aN;
#pragma unroll
    for (int nf = 0; nf < 4; ++nf) bC[nf] = bN[nf];
  }

  // relu*gate -> lS (bf16)
  int trow = wr * 16 + grp * 4;
#pragma unroll
  for (int nf = 0; nf < 4; ++nf) {
    int e = wc * 64 + nf * 16 + col;
#pragma unroll
    for (int r = 0; r < 4; ++r) {
      float s = acc[nf][r];
      s = s > 0.0f ? s * sGate[trow + r] : 0.0f;
      lS[trow + r][e] = f2bf(s);
    }
  }
  __syncthreads();

  // ---- GEMM2: wave (wr,wc) -> tokens [wr*16,+16), v-cols ch*64 + wc*32 + [0,32)
  bf16x8 aS[4];
#pragma unroll
  for (int kc = 0; kc < 4; ++kc)
    aS[kc] = *reinterpret_cast<const bf16x8*>(&lS[wr * 16 + col][kc * 32 + grp * 8]);

  unsigned short* rp[4];
#pragma unroll
  for (int r = 0; r < 4; ++r)
    rp[r] = part + (size_t)sRow[wr * 16 + grp * 4 + r] * DMODEL + wc * 32 + col;

  const unsigned short* vP[2];
#pragma unroll
  for (int nf = 0; nf < 2; ++nf)
    vP[nf] = vb + (size_t)(wc * 32 + nf * 16 + col) * ESIZE + grp * 8;

  bf16x8 vc[8], vn[8];
#pragma unroll
  for (int nf = 0; nf < 2; ++nf)
#pragma unroll
    for (int kc = 0; kc < 4; ++kc)
      vc[nf * 4 + kc] = *reinterpret_cast<const bf16x8*>(vP[nf] + kc * 32);

#pragma unroll 2
  for (int ch = 0; ch < 16; ++ch) {
    size_t chN = (size_t)((ch + 1) & 15) * 64 * ESIZE;
#pragma unroll
    for (int nf = 0; nf < 2; ++nf)
#pragma unroll
      for (int kc = 0; kc < 4; ++kc)
        vn[nf * 4 + kc] = *reinterpret_cast<const bf16x8*>(vP[nf] + chN + kc * 32);
    f32x4 o0 = {}, o1 = {};
#pragma unroll
    for (int kc = 0; kc < 4; ++kc) {
      o0 = __builtin_amdgcn_mfma_f32_16x16x32_bf16(aS[kc], vc[kc], o0, 0, 0, 0);
      o1 = __builtin_amdgcn_mfma_f32_16x16x32_bf16(aS[kc], vc[4 + kc], o1, 0, 0, 0);
    }
#pragma unroll
    for (int r = 0; r < 4; ++r) {
      rp[r][ch * 64] = f2bf(o0[r]);
      rp[r][ch * 64 + 16] = f2bf(o1[r]);
    }
#pragma unroll
    for (int j = 0; j < 8; ++j) vc[j] = vn[j];
  }
}

// K7: out[n][v] = sum_h part[h*N_TOK+n][v]  (bf16 partials -> fp32 out, full overwrite)
__global__ void k_sum(const unsigned short* __restrict__ part, float* __restrict__ out) {
  size_t i = ((size_t)blockIdx.x * 256 + threadIdx.x) * 8;
  const size_t stride = (size_t)N_TOK * DMODEL;
  uint4 a = *reinterpret_cast<const uint4*>(part + i);
  uint4 b = *reinterpret_cast<const uint4*>(part + stride + i);
  uint4 c = *reinterpret_cast<const uint4*>(part + 2 * stride + i);
  uint4 d = *reinterpret_cast<const uint4*>(part + 3 * stride + i);
  float o[8];
#pragma unroll
  for (int q = 0; q < 4; ++q) {
    unsigned ua = (&a.x)[q], ub = (&b.x)[q], uc = (&c.x)[q], ud = (&d.x)[q];
    o[q * 2 + 0] = b2f((unsigned short)ua) + b2f((unsigned short)ub) +
                   b2f((unsigned short)uc) + b2f((unsigned short)ud);
    o[q * 2 + 1] = b2f((unsigned short)(ua >> 16)) + b2f((unsigned short)(ub >> 16)) +
                   b2f((unsigned short)(uc >> 16)) + b2f((unsigned short)(ud >> 16));
  }
  *reinterpret_cast<float4*>(out + i) = make_float4(o[0], o[1], o[2], o[3]);
  *reinterpret_cast<float4*>(out + i + 4) = make_float4(o[4], o[5], o[6], o[7]);
}

extern "C" void kernel_launch(void* const* d_in, const int* in_sizes, int n_in,
                              void* d_out, int out_size, void* d_ws, size_t ws_size,
                              hipStream_t stream) {
  const float* x = (const float*)d_in[0];
  const float* esel = (const float*)d_in[1];
  const float* keys = (const float*)d_in[2];
  const float* values = (const float*)d_in[3];
  float* out = (float*)d_out;

  char* p = (char*)d_ws;
  unsigned short* xbf = (unsigned short*)p; p += (size_t)N_TOK * DMODEL * 2;
  unsigned short* kbf = (unsigned short*)p; p += (size_t)NEXP * DMODEL * ESIZE * 2;
  unsigned short* vbf = (unsigned short*)p; p += (size_t)NEXP * DMODEL * ESIZE * 2;
  float* selT = (float*)p; p += (size_t)DMODEL * NEXP * 4;
  float4* g4 = (float4*)p; p += (size_t)N_TOK * 16;
  int4* idx4 = (int4*)p; p += (size_t)N_TOK * 16;
  int* btok = (int*)p; p += (size_t)NEXP * N_TOK * 4;
  float* bgate = (float*)p; p += (size_t)NEXP * N_TOK * 4;
  unsigned short* part = (unsigned short*)p;
  p += ((size_t)4 * N_TOK + WL_MAX) * DMODEL * 2;  // + per-block dump rows
  int* cnt = (int*)p; p += 256;
  int* wl = (int*)p; p += WL_MAX * 4;
  (void)ws_size; (void)in_sizes; (void)n_in;

  hipMemsetAsync(cnt, 0, 64 * sizeof(int), stream);
  k_selT<<<256, 256, 0, stream>>>(esel, selT);
  k_castx<<<(N_TOK * DMODEL / 8) / 256, 256, 0, stream>>>(x, xbf);
  k_transpose<<<dim3(128, 64), 256, 0, stream>>>(keys, kbf, DMODEL, ESIZE);
  k_transpose<<<dim3(128, 64), 256, 0, stream>>>(values, vbf, ESIZE, DMODEL);
  k_router<<<256, 256, 0, stream>>>(x, selT, idx4, g4);
  k_bucket<<<32, 256, 0, stream>>>(idx4, g4, btok, bgate, cnt);
  k_worklist<<<1, 64, 0, stream>>>(cnt, wl);
  k_expert<<<WL_MAX, 256, 0, stream>>>(xbf, kbf, vbf, wl, btok, bgate, cnt, part);
  k_sum<<<(N_TOK * DMODEL / 8) / 256, 256, 0, stream>>>(part, out);
}

// Round 5
// 192.628 us; speedup vs baseline: 1.5191x; 1.5191x over previous
//
#include <hip/hip_runtime.h>

typedef __bf16 bf16x8 __attribute__((ext_vector_type(8)));
typedef float f32x4 __attribute__((ext_vector_type(4)));

#define N_TOK 8192
#define DMODEL 1024
#define NEXP 64
#define ESIZE 128
#define WL_MAX 320   // sum ceil(ck/128) <= 32768/128 + 64 = 320 (divisible by 8)

__device__ __forceinline__ unsigned short f2bf(float f) {
  unsigned int u = __builtin_bit_cast(unsigned int, f);
  u += 0x7FFFu + ((u >> 16) & 1u);
  return (unsigned short)(u >> 16);
}

__device__ __forceinline__ float b2f(unsigned short u) {
  unsigned int v = ((unsigned int)u) << 16;
  return __builtin_bit_cast(float, v);
}

// async global->LDS, 16B per lane. LDS dest must be lane-linear within the wave.
__device__ __forceinline__ void gld16(unsigned short* lds, const unsigned short* g) {
  __builtin_amdgcn_global_load_lds(
      (const __attribute__((address_space(1))) unsigned int*)g,
      (__attribute__((address_space(3))) unsigned int*)lds, 16, 0, 0);
}

// K0: expert_sel [64][1024] -> selT [1024][64] fp32
__global__ void k_selT(const float* __restrict__ in, float* __restrict__ outT) {
  int id = blockIdx.x * 256 + threadIdx.x;
  int e = id & 63, j = id >> 6;
  outT[id] = in[e * DMODEL + j];
}

// K1: x fp32 -> bf16
__global__ void k_castx(const float* __restrict__ in, unsigned short* __restrict__ out) {
  size_t i = (size_t)(blockIdx.x * 256 + threadIdx.x) * 8;
  float4 a = *reinterpret_cast<const float4*>(in + i);
  float4 b = *reinterpret_cast<const float4*>(in + i + 4);
  uint4 o;
  o.x = f2bf(a.x) | ((unsigned)f2bf(a.y) << 16);
  o.y = f2bf(a.z) | ((unsigned)f2bf(a.w) << 16);
  o.z = f2bf(b.x) | ((unsigned)f2bf(b.y) << 16);
  o.w = f2bf(b.z) | ((unsigned)f2bf(b.w) << 16);
  *reinterpret_cast<uint4*>(out + i) = o;
}

// K2: per-expert transpose+cast: in [B][R][C] f32 -> out [B][C][R] bf16
__global__ void k_transpose(const float* __restrict__ in, unsigned short* __restrict__ out,
                            int R, int C) {
  __shared__ float t[32][33];
  int b = blockIdx.y;
  int tilesC = C >> 5;
  int tr = blockIdx.x / tilesC, tc = blockIdx.x % tilesC;
  int lr = threadIdx.x >> 5, lc = threadIdx.x & 31;
  const float* ip = in + (size_t)b * R * C;
  unsigned short* op = out + (size_t)b * R * C;
#pragma unroll
  for (int p = 0; p < 4; ++p)
    t[p * 8 + lr][lc] = ip[(size_t)(tr * 32 + p * 8 + lr) * C + tc * 32 + lc];
  __syncthreads();
#pragma unroll
  for (int p = 0; p < 4; ++p)
    op[(size_t)(tc * 32 + p * 8 + lr) * R + tr * 32 + lc] = f2bf(t[lc][p * 8 + lr]);
}

// K3: router — LDS-tiled fp64-accum GEMM (rank fidelity) + per-token top-4.
__global__ __launch_bounds__(256) void k_router(const float* __restrict__ x,
                                                const float* __restrict__ selT,
                                                int4* __restrict__ idx4,
                                                float4* __restrict__ g4) {
  int tid = threadIdx.x;
  int tok0 = blockIdx.x * 32;
  int ty = tid >> 4, tx = tid & 15;
  __shared__ float lx[32][34];
  __shared__ float ls[32][64];
  __shared__ double lg[32][65];

  int tokr = tid >> 3, dseg = (tid & 7) * 4;
  int srow = tid >> 3, scol = (tid & 7) * 8;

  double acc[2][4];
#pragma unroll
  for (int r = 0; r < 2; ++r)
#pragma unroll
    for (int c = 0; c < 4; ++c) acc[r][c] = 0.0;

  for (int cc = 0; cc < DMODEL; cc += 32) {
    float4 xv = *reinterpret_cast<const float4*>(&x[(size_t)(tok0 + tokr) * DMODEL + cc + dseg]);
    lx[dseg + 0][tokr] = xv.x;
    lx[dseg + 1][tokr] = xv.y;
    lx[dseg + 2][tokr] = xv.z;
    lx[dseg + 3][tokr] = xv.w;
    *reinterpret_cast<float4*>(&ls[srow][scol]) =
        *reinterpret_cast<const float4*>(&selT[(size_t)(cc + srow) * 64 + scol]);
    *reinterpret_cast<float4*>(&ls[srow][scol + 4]) =
        *reinterpret_cast<const float4*>(&selT[(size_t)(cc + srow) * 64 + scol + 4]);
    __syncthreads();
#pragma unroll
    for (int j = 0; j < 32; ++j) {
      float2 xj = *reinterpret_cast<const float2*>(&lx[j][ty * 2]);
      float4 sj = *reinterpret_cast<const float4*>(&ls[j][tx * 4]);
      double x0 = (double)xj.x, x1 = (double)xj.y;
      double s0 = (double)sj.x, s1 = (double)sj.y, s2 = (double)sj.z, s3 = (double)sj.w;
      acc[0][0] += x0 * s0; acc[0][1] += x0 * s1; acc[0][2] += x0 * s2; acc[0][3] += x0 * s3;
      acc[1][0] += x1 * s0; acc[1][1] += x1 * s1; acc[1][2] += x1 * s2; acc[1][3] += x1 * s3;
    }
    __syncthreads();
  }

#pragma unroll
  for (int r = 0; r < 2; ++r)
#pragma unroll
    for (int c = 0; c < 4; ++c) lg[ty * 2 + r][tx * 4 + c] = acc[r][c];
  __syncthreads();

  if (tid < 32) {
    double bv0 = -1.0e300, bv1 = -1.0e300, bv2 = -1.0e300, bv3 = -1.0e300;
    int bi0 = 0, bi1 = 0, bi2 = 0, bi3 = 0;
    for (int e = 0; e < 64; ++e) {
      double v = lg[tid][e];
      if (v > bv3) {
        if (v > bv0) {
          bv3 = bv2; bi3 = bi2; bv2 = bv1; bi2 = bi1; bv1 = bv0; bi1 = bi0; bv0 = v; bi0 = e;
        } else if (v > bv1) {
          bv3 = bv2; bi3 = bi2; bv2 = bv1; bi2 = bi1; bv1 = v; bi1 = e;
        } else if (v > bv2) {
          bv3 = bv2; bi3 = bi2; bv2 = v; bi2 = e;
        } else {
          bv3 = v; bi3 = e;
        }
      }
    }
    idx4[tok0 + tid] = make_int4(bi0, bi1, bi2, bi3);
    float4 g;
    g.x = 1.0f / (1.0f + __expf(-(float)bv0));
    g.y = 1.0f / (1.0f + __expf(-(float)bv1));
    g.z = 1.0f / (1.0f + __expf(-(float)bv2));
    g.w = 1.0f / (1.0f + __expf(-(float)bv3));
    g4[tok0 + tid] = g;
  }
}

// K4: two-level atomic bucketize. Slot order within a bucket is non-deterministic,
// but each part-row (head,token) is written exactly once -> output invariant.
__global__ __launch_bounds__(256) void k_bucket(const int4* __restrict__ idx4,
                                                const float4* __restrict__ g4,
                                                int* __restrict__ btok,
                                                float* __restrict__ bgate,
                                                int* __restrict__ cnt) {
  __shared__ int lcnt[64];
  __shared__ int lbase[64];
  int tid = threadIdx.x;
  if (tid < 64) lcnt[tid] = 0;
  __syncthreads();
  int n = blockIdx.x * 256 + tid;
  int4 I = idx4[n];
  float4 G = g4[n];
  int e[4] = {I.x, I.y, I.z, I.w};
  float g[4] = {G.x, G.y, G.z, G.w};
  int pos[4];
#pragma unroll
  for (int h = 0; h < 4; ++h) pos[h] = atomicAdd(&lcnt[e[h]], 1);
  __syncthreads();
  if (tid < 64 && lcnt[tid] > 0) lbase[tid] = atomicAdd(&cnt[tid], lcnt[tid]);
  __syncthreads();
#pragma unroll
  for (int h = 0; h < 4; ++h) {
    int slot = lbase[e[h]] + pos[h];
    btok[e[h] * N_TOK + slot] = h * N_TOK + n;
    bgate[e[h] * N_TOK + slot] = g[h];
  }
}

// K5: compact worklist of (expert, tile128) pairs. 1 block, 64 threads.
__global__ void k_worklist(const int* __restrict__ cnt, int* __restrict__ wl) {
  int lane = threadIdx.x;
  int nt = (cnt[lane] + 127) >> 7;
  int off = nt;
  for (int d = 1; d < 64; d <<= 1) {
    int o = __shfl_up(off, d);
    if (lane >= d) off += o;
  }
  int total = __shfl(off, 63);
  off -= nt;
  for (int t = 0; t < nt; ++t) wl[off + t] = (lane << 8) | t;
  for (int i = total + lane; i < WL_MAX; i += 64) wl[i] = -1;
}

// K6: fused per-(expert,tile128). m97-style: global_load_lds(16B) bulk staging,
// 2-barrier k-loop, XOR source-swizzled LDS (conflict-free ds_read_b128).
// 512 threads = 8 waves (2 token-halves x 4 col-quarters).
__global__ __launch_bounds__(512, 2) void k_expert(
    const unsigned short* __restrict__ xbf, const unsigned short* __restrict__ kbf,
    const unsigned short* __restrict__ vbf, const int* __restrict__ wl,
    const int* __restrict__ btok, const float* __restrict__ bgate,
    const int* __restrict__ cnt, unsigned short* __restrict__ part) {
  int wid = (blockIdx.x & 7) * (WL_MAX / 8) + (blockIdx.x >> 3);
  int wle = wl[wid];
  if (wle < 0) return;
  int k = wle >> 8, tile = wle & 255;
  int ck = cnt[k];
  int tid = threadIdx.x, lane = tid & 63;
  int wv = tid >> 6, wr = wv >> 2, wc = wv & 3;
  int cc = lane & 15, grp = lane >> 4;

  __shared__ alignas(16) unsigned short stage[16384];     // 32 KB bulk-staging buffer
  __shared__ alignas(16) unsigned short lS[128 * 136];    // scores, padded stride
  __shared__ int sRow[128];
  __shared__ float sGate[128];

  if (tid < 128) {
    int i = tile * 128 + tid;
    bool valid = i < ck;
    sRow[tid] = valid ? btok[k * N_TOK + i] : 4 * N_TOK + wid;  // per-block dump row
    sGate[tid] = valid ? bgate[k * N_TOK + i] : 0.0f;
  }
  __syncthreads();

  const unsigned short* kb = kbf + (size_t)k * (ESIZE * DMODEL);
  const unsigned short* vb = vbf + (size_t)k * (DMODEL * ESIZE);
  const char* sb = (const char*)stage;

  // ---- GEMM1: S[128 tok][128 e] = X · K^T, K=1024, BK=64, A+B staged (16+16 KB)
  // per-thread staging bases: 2 slots each for A and B; slot = (row, phys-chunk)
  // source chunk = phys ^ (row&7)  (inverse of the read-side swizzle)
  int slot0 = tid, slot1 = tid + 512;
  int ar0 = slot0 >> 3, ar1 = slot1 >> 3;
  const unsigned short* srcA0 =
      xbf + (size_t)(sRow[ar0] & (N_TOK - 1)) * DMODEL + (((slot0 & 7) ^ (ar0 & 7)) * 8);
  const unsigned short* srcA1 =
      xbf + (size_t)(sRow[ar1] & (N_TOK - 1)) * DMODEL + (((slot1 & 7) ^ (ar1 & 7)) * 8);
  const unsigned short* srcB0 = kb + (size_t)ar0 * DMODEL + (((slot0 & 7) ^ (ar0 & 7)) * 8);
  const unsigned short* srcB1 = kb + (size_t)ar1 * DMODEL + (((slot1 & 7) ^ (ar1 & 7)) * 8);
  unsigned short* dA0 = &stage[slot0 * 8];
  unsigned short* dA1 = &stage[slot1 * 8];
  unsigned short* dB0 = &stage[8192 + slot0 * 8];
  unsigned short* dB1 = &stage[8192 + slot1 * 8];

  f32x4 acc[4][2] = {};
  for (int kk = 0; kk < DMODEL; kk += 64) {
    gld16(dA0, srcA0 + kk);
    gld16(dA1, srcA1 + kk);
    gld16(dB0, srcB0 + kk);
    gld16(dB1, srcB1 + kk);
    __syncthreads();   // drains vmcnt -> staged data visible
    bf16x8 aF[2][4], bF[2][2];
#pragma unroll
    for (int ks = 0; ks < 2; ++ks) {
#pragma unroll
      for (int m = 0; m < 4; ++m) {
        int r = wr * 64 + m * 16 + cc;
        aF[ks][m] = *reinterpret_cast<const bf16x8*>(sb + r * 128 + (((ks * 4 + grp) ^ (r & 7)) * 16));
      }
#pragma unroll
      for (int n = 0; n < 2; ++n) {
        int r = wc * 32 + n * 16 + cc;
        bF[ks][n] = *reinterpret_cast<const bf16x8*>(sb + 16384 + r * 128 + (((ks * 4 + grp) ^ (r & 7)) * 16));
      }
    }
#pragma unroll
    for (int ks = 0; ks < 2; ++ks)
#pragma unroll
      for (int m = 0; m < 4; ++m)
#pragma unroll
        for (int n = 0; n < 2; ++n)
          acc[m][n] = __builtin_amdgcn_mfma_f32_16x16x32_bf16(aF[ks][m], bF[ks][n], acc[m][n], 0, 0, 0);
    __syncthreads();   // safe to overwrite stage next iter
  }

  // relu*gate -> lS
#pragma unroll
  for (int m = 0; m < 4; ++m) {
    int trow = wr * 64 + m * 16 + grp * 4;
#pragma unroll
    for (int n = 0; n < 2; ++n) {
      int e = wc * 32 + n * 16 + cc;
#pragma unroll
      for (int r = 0; r < 4; ++r) {
        float s = acc[m][n][r];
        s = s > 0.0f ? s * sGate[trow + r] : 0.0f;
        lS[(trow + r) * 136 + e] = f2bf(s);
      }
    }
  }
  __syncthreads();

  // ---- GEMM2: out[128 tok][1024] = S · V, K=128; V staged 128x128 per nb-chunk
  // S-frags preloaded (reused across all 8 chunks)
  bf16x8 sF[4][4];
#pragma unroll
  for (int m = 0; m < 4; ++m) {
    int r = wr * 64 + m * 16 + cc;
#pragma unroll
    for (int ks = 0; ks < 4; ++ks)
      sF[m][ks] = *reinterpret_cast<const bf16x8*>((const char*)lS + r * 272 + ks * 64 + grp * 16);
  }
  // V staging bases: 4 slots/thread; row stride 256B -> 16 chunks, swz mask (row&15)
  const unsigned short* srcV[4];
  unsigned short* dV[4];
#pragma unroll
  for (int rd = 0; rd < 4; ++rd) {
    int slot = rd * 512 + tid;
    int row = slot >> 4, pcv = slot & 15;
    srcV[rd] = vb + (size_t)row * ESIZE + ((pcv ^ (row & 15)) * 8);
    dV[rd] = &stage[slot * 8];
  }
  // output row base pointers
  unsigned short* rB[4][4];
#pragma unroll
  for (int m = 0; m < 4; ++m)
#pragma unroll
    for (int r = 0; r < 4; ++r)
      rB[m][r] = part + (size_t)sRow[wr * 64 + m * 16 + grp * 4 + r] * DMODEL + wc * 32 + cc;

  for (int nb = 0; nb < 8; ++nb) {
#pragma unroll
    for (int rd = 0; rd < 4; ++rd) gld16(dV[rd], srcV[rd] + nb * 128 * ESIZE);
    __syncthreads();
    bf16x8 vF[4][2];
#pragma unroll
    for (int ks = 0; ks < 4; ++ks)
#pragma unroll
      for (int n = 0; n < 2; ++n) {
        int r = wc * 32 + n * 16 + cc;
        vF[ks][n] = *reinterpret_cast<const bf16x8*>(sb + r * 256 + (((ks * 4 + grp) ^ (r & 15)) * 16));
      }
    f32x4 o[4][2] = {};
#pragma unroll
    for (int ks = 0; ks < 4; ++ks)
#pragma unroll
      for (int m = 0; m < 4; ++m)
#pragma unroll
        for (int n = 0; n < 2; ++n)
          o[m][n] = __builtin_amdgcn_mfma_f32_16x16x32_bf16(sF[m][ks], vF[ks][n], o[m][n], 0, 0, 0);
#pragma unroll
    for (int m = 0; m < 4; ++m)
#pragma unroll
      for (int n = 0; n < 2; ++n)
#pragma unroll
        for (int r = 0; r < 4; ++r)
          rB[m][r][nb * 128 + n * 16] = f2bf(o[m][n][r]);
    __syncthreads();
  }
}

// K7: out[n][v] = sum_h part[h*N_TOK+n][v]  (bf16 partials -> fp32 out, full overwrite)
__global__ void k_sum(const unsigned short* __restrict__ part, float* __restrict__ out) {
  size_t i = ((size_t)blockIdx.x * 256 + threadIdx.x) * 8;
  const size_t stride = (size_t)N_TOK * DMODEL;
  uint4 a = *reinterpret_cast<const uint4*>(part + i);
  uint4 b = *reinterpret_cast<const uint4*>(part + stride + i);
  uint4 c = *reinterpret_cast<const uint4*>(part + 2 * stride + i);
  uint4 d = *reinterpret_cast<const uint4*>(part + 3 * stride + i);
  float o[8];
#pragma unroll
  for (int q = 0; q < 4; ++q) {
    unsigned ua = (&a.x)[q], ub = (&b.x)[q], uc = (&c.x)[q], ud = (&d.x)[q];
    o[q * 2 + 0] = b2f((unsigned short)ua) + b2f((unsigned short)ub) +
                   b2f((unsigned short)uc) + b2f((unsigned short)ud);
    o[q * 2 + 1] = b2f((unsigned short)(ua >> 16)) + b2f((unsigned short)(ub >> 16)) +
                   b2f((unsigned short)(uc >> 16)) + b2f((unsigned short)(ud >> 16));
  }
  *reinterpret_cast<float4*>(out + i) = make_float4(o[0], o[1], o[2], o[3]);
  *reinterpret_cast<float4*>(out + i + 4) = make_float4(o[4], o[5], o[6], o[7]);
}

extern "C" void kernel_launch(void* const* d_in, const int* in_sizes, int n_in,
                              void* d_out, int out_size, void* d_ws, size_t ws_size,
                              hipStream_t stream) {
  const float* x = (const float*)d_in[0];
  const float* esel = (const float*)d_in[1];
  const float* keys = (const float*)d_in[2];
  const float* values = (const float*)d_in[3];
  float* out = (float*)d_out;

  char* p = (char*)d_ws;
  unsigned short* xbf = (unsigned short*)p; p += (size_t)N_TOK * DMODEL * 2;
  unsigned short* kbf = (unsigned short*)p; p += (size_t)NEXP * DMODEL * ESIZE * 2;
  unsigned short* vbf = (unsigned short*)p; p += (size_t)NEXP * DMODEL * ESIZE * 2;
  float* selT = (float*)p; p += (size_t)DMODEL * NEXP * 4;
  float4* g4 = (float4*)p; p += (size_t)N_TOK * 16;
  int4* idx4 = (int4*)p; p += (size_t)N_TOK * 16;
  int* btok = (int*)p; p += (size_t)NEXP * N_TOK * 4;
  float* bgate = (float*)p; p += (size_t)NEXP * N_TOK * 4;
  unsigned short* part = (unsigned short*)p;
  p += ((size_t)4 * N_TOK + WL_MAX) * DMODEL * 2;  // + per-block dump rows
  int* cnt = (int*)p; p += 256;
  int* wl = (int*)p; p += WL_MAX * 4;
  (void)ws_size; (void)in_sizes; (void)n_in;

  hipMemsetAsync(cnt, 0, 64 * sizeof(int), stream);
  k_selT<<<256, 256, 0, stream>>>(esel, selT);
  k_castx<<<(N_TOK * DMODEL / 8) / 256, 256, 0, stream>>>(x, xbf);
  k_transpose<<<dim3(128, 64), 256, 0, stream>>>(keys, kbf, DMODEL, ESIZE);
  k_transpose<<<dim3(128, 64), 256, 0, stream>>>(values, vbf, ESIZE, DMODEL);
  k_router<<<256, 256, 0, stream>>>(x, selT, idx4, g4);
  k_bucket<<<32, 256, 0, stream>>>(idx4, g4, btok, bgate, cnt);
  k_worklist<<<1, 64, 0, stream>>>(cnt, wl);
  k_expert<<<WL_MAX, 512, 0, stream>>>(xbf, kbf, vbf, wl, btok, bgate, cnt, part);
  k_sum<<<(N_TOK * DMODEL / 8) / 256, 256, 0, stream>>>(part, out);
}

// Round 6
// 173.737 us; speedup vs baseline: 1.6843x; 1.1087x over previous
//
#include <hip/hip_runtime.h>

typedef __bf16 bf16x8 __attribute__((ext_vector_type(8)));
typedef float f32x4 __attribute__((ext_vector_type(4)));

#define N_TOK 8192
#define DMODEL 1024
#define NEXP 64
#define ESIZE 128
#define WL_MAX 576   // sum ceil(ck/64) <= 32768/64 + 64 = 576 (divisible by 8)

__device__ __forceinline__ unsigned short f2bf(float f) {
  unsigned int u = __builtin_bit_cast(unsigned int, f);
  u += 0x7FFFu + ((u >> 16) & 1u);
  return (unsigned short)(u >> 16);
}

__device__ __forceinline__ float b2f(unsigned short u) {
  unsigned int v = ((unsigned int)u) << 16;
  return __builtin_bit_cast(float, v);
}

// async global->LDS, 16B per lane. LDS dest lane-linear within the wave.
__device__ __forceinline__ void gld16(unsigned short* lds, const unsigned short* g) {
  __builtin_amdgcn_global_load_lds(
      (const __attribute__((address_space(1))) unsigned int*)g,
      (__attribute__((address_space(3))) unsigned int*)lds, 16, 0, 0);
}

// K0: expert_sel [64][1024] -> selT [1024][64] fp32
__global__ void k_selT(const float* __restrict__ in, float* __restrict__ outT) {
  int id = blockIdx.x * 256 + threadIdx.x;
  int e = id & 63, j = id >> 6;
  outT[id] = in[e * DMODEL + j];
}

// K2: per-expert transpose+cast: in [B][R][C] f32 -> out [B][C][R] bf16
__global__ void k_transpose(const float* __restrict__ in, unsigned short* __restrict__ out,
                            int R, int C) {
  __shared__ float t[32][33];
  int b = blockIdx.y;
  int tilesC = C >> 5;
  int tr = blockIdx.x / tilesC, tc = blockIdx.x % tilesC;
  int lr = threadIdx.x >> 5, lc = threadIdx.x & 31;
  const float* ip = in + (size_t)b * R * C;
  unsigned short* op = out + (size_t)b * R * C;
#pragma unroll
  for (int p = 0; p < 4; ++p)
    t[p * 8 + lr][lc] = ip[(size_t)(tr * 32 + p * 8 + lr) * C + tc * 32 + lc];
  __syncthreads();
#pragma unroll
  for (int p = 0; p < 4; ++p)
    op[(size_t)(tc * 32 + p * 8 + lr) * R + tr * 32 + lc] = f2bf(t[lc][p * 8 + lr]);
}

// K3: router — LDS-tiled fp64-accum GEMM (rank fidelity) + per-token top-4.
// Also writes the bf16 copy of x (fused former k_castx).
__global__ __launch_bounds__(256) void k_router(const float* __restrict__ x,
                                                const float* __restrict__ selT,
                                                unsigned short* __restrict__ xbf,
                                                int4* __restrict__ idx4,
                                                float4* __restrict__ g4) {
  int tid = threadIdx.x;
  int tok0 = blockIdx.x * 32;
  int ty = tid >> 4, tx = tid & 15;
  __shared__ float lx[32][34];
  __shared__ float ls[32][64];
  __shared__ double lg[32][65];

  int tokr = tid >> 3, dseg = (tid & 7) * 4;
  int srow = tid >> 3, scol = (tid & 7) * 8;

  double acc[2][4];
#pragma unroll
  for (int r = 0; r < 2; ++r)
#pragma unroll
    for (int c = 0; c < 4; ++c) acc[r][c] = 0.0;

  for (int cc = 0; cc < DMODEL; cc += 32) {
    float4 xv = *reinterpret_cast<const float4*>(&x[(size_t)(tok0 + tokr) * DMODEL + cc + dseg]);
    // fused bf16 cast-out of x
    unsigned int p0 = f2bf(xv.x) | ((unsigned)f2bf(xv.y) << 16);
    unsigned int p1 = f2bf(xv.z) | ((unsigned)f2bf(xv.w) << 16);
    *reinterpret_cast<uint2*>(&xbf[(size_t)(tok0 + tokr) * DMODEL + cc + dseg]) =
        make_uint2(p0, p1);
    lx[dseg + 0][tokr] = xv.x;
    lx[dseg + 1][tokr] = xv.y;
    lx[dseg + 2][tokr] = xv.z;
    lx[dseg + 3][tokr] = xv.w;
    *reinterpret_cast<float4*>(&ls[srow][scol]) =
        *reinterpret_cast<const float4*>(&selT[(size_t)(cc + srow) * 64 + scol]);
    *reinterpret_cast<float4*>(&ls[srow][scol + 4]) =
        *reinterpret_cast<const float4*>(&selT[(size_t)(cc + srow) * 64 + scol + 4]);
    __syncthreads();
#pragma unroll
    for (int j = 0; j < 32; ++j) {
      float2 xj = *reinterpret_cast<const float2*>(&lx[j][ty * 2]);
      float4 sj = *reinterpret_cast<const float4*>(&ls[j][tx * 4]);
      double x0 = (double)xj.x, x1 = (double)xj.y;
      double s0 = (double)sj.x, s1 = (double)sj.y, s2 = (double)sj.z, s3 = (double)sj.w;
      acc[0][0] += x0 * s0; acc[0][1] += x0 * s1; acc[0][2] += x0 * s2; acc[0][3] += x0 * s3;
      acc[1][0] += x1 * s0; acc[1][1] += x1 * s1; acc[1][2] += x1 * s2; acc[1][3] += x1 * s3;
    }
    __syncthreads();
  }

#pragma unroll
  for (int r = 0; r < 2; ++r)
#pragma unroll
    for (int c = 0; c < 4; ++c) lg[ty * 2 + r][tx * 4 + c] = acc[r][c];
  __syncthreads();

  if (tid < 32) {
    double bv0 = -1.0e300, bv1 = -1.0e300, bv2 = -1.0e300, bv3 = -1.0e300;
    int bi0 = 0, bi1 = 0, bi2 = 0, bi3 = 0;
    for (int e = 0; e < 64; ++e) {
      double v = lg[tid][e];
      if (v > bv3) {
        if (v > bv0) {
          bv3 = bv2; bi3 = bi2; bv2 = bv1; bi2 = bi1; bv1 = bv0; bi1 = bi0; bv0 = v; bi0 = e;
        } else if (v > bv1) {
          bv3 = bv2; bi3 = bi2; bv2 = bv1; bi2 = bi1; bv1 = v; bi1 = e;
        } else if (v > bv2) {
          bv3 = bv2; bi3 = bi2; bv2 = v; bi2 = e;
        } else {
          bv3 = v; bi3 = e;
        }
      }
    }
    idx4[tok0 + tid] = make_int4(bi0, bi1, bi2, bi3);
    float4 g;
    g.x = 1.0f / (1.0f + __expf(-(float)bv0));
    g.y = 1.0f / (1.0f + __expf(-(float)bv1));
    g.z = 1.0f / (1.0f + __expf(-(float)bv2));
    g.w = 1.0f / (1.0f + __expf(-(float)bv3));
    g4[tok0 + tid] = g;
  }
}

// K4: two-level atomic bucketize (slot order non-deterministic; output invariant).
__global__ __launch_bounds__(256) void k_bucket(const int4* __restrict__ idx4,
                                                const float4* __restrict__ g4,
                                                int* __restrict__ btok,
                                                float* __restrict__ bgate,
                                                int* __restrict__ cnt) {
  __shared__ int lcnt[64];
  __shared__ int lbase[64];
  int tid = threadIdx.x;
  if (tid < 64) lcnt[tid] = 0;
  __syncthreads();
  int n = blockIdx.x * 256 + tid;
  int4 I = idx4[n];
  float4 G = g4[n];
  int e[4] = {I.x, I.y, I.z, I.w};
  float g[4] = {G.x, G.y, G.z, G.w};
  int pos[4];
#pragma unroll
  for (int h = 0; h < 4; ++h) pos[h] = atomicAdd(&lcnt[e[h]], 1);
  __syncthreads();
  if (tid < 64 && lcnt[tid] > 0) lbase[tid] = atomicAdd(&cnt[tid], lcnt[tid]);
  __syncthreads();
#pragma unroll
  for (int h = 0; h < 4; ++h) {
    int slot = lbase[e[h]] + pos[h];
    btok[e[h] * N_TOK + slot] = h * N_TOK + n;
    bgate[e[h] * N_TOK + slot] = g[h];
  }
}

// K5: compact worklist of (expert, tile64) pairs. 1 block, 64 threads.
__global__ void k_worklist(const int* __restrict__ cnt, int* __restrict__ wl) {
  int lane = threadIdx.x;
  int nt = (cnt[lane] + 63) >> 6;
  int off = nt;
  for (int d = 1; d < 64; d <<= 1) {
    int o = __shfl_up(off, d);
    if (lane >= d) off += o;
  }
  int total = __shfl(off, 63);
  off -= nt;
  for (int t = 0; t < nt; ++t) wl[off + t] = (lane << 8) | t;
  for (int i = total + lane; i < WL_MAX; i += 64) wl[i] = -1;
}

// K6: fused per-(expert,tile64). global_load_lds bulk staging with DOUBLE-BUFFERED
// 2-phase prefetch (issue next-step loads, then ds_read+MFMA current, one barrier).
// 512 threads = 8 waves (2 token-halves x 4 col-quarters). LDS 65.5KB -> 2 blocks/CU.
__global__ __launch_bounds__(512, 4) void k_expert(
    const unsigned short* __restrict__ xbf, const unsigned short* __restrict__ kbf,
    const unsigned short* __restrict__ vbf, const int* __restrict__ wl,
    const int* __restrict__ btok, const float* __restrict__ bgate,
    const int* __restrict__ cnt, unsigned short* __restrict__ part) {
  int wid = (blockIdx.x & 7) * (WL_MAX / 8) + (blockIdx.x >> 3);
  int wle = wl[wid];
  if (wle < 0) return;
  int k = wle >> 8, tile = wle & 255;
  int ck = cnt[k];
  int tid = threadIdx.x, lane = tid & 63;
  int wv = tid >> 6, wr = wv >> 2, wc = wv & 3;
  int cc = lane & 15, grp = lane >> 4;

  __shared__ alignas(16) unsigned short stage[24576];  // 48 KB: 2 x (A 8KB + B 16KB)
  __shared__ alignas(16) unsigned short lS[64 * 136];  // 17.4 KB scores
  __shared__ int sRow[64];
  __shared__ float sGate[64];

  if (tid < 64) {
    int i = tile * 64 + tid;
    bool valid = i < ck;
    sRow[tid] = valid ? btok[k * N_TOK + i] : 4 * N_TOK + wid;  // per-block dump row
    sGate[tid] = valid ? bgate[k * N_TOK + i] : 0.0f;
  }
  __syncthreads();

  const unsigned short* kb = kbf + (size_t)k * (ESIZE * DMODEL);
  const unsigned short* vb = vbf + (size_t)k * (DMODEL * ESIZE);
  char* sbase = (char*)stage;

  // ---- GEMM1 staging bases (src chunk = phys ^ (row&7), LDS dest lane-linear)
  int arow = tid >> 3, ach = tid & 7;
  const unsigned short* srcA =
      xbf + (size_t)(sRow[arow] & (N_TOK - 1)) * DMODEL + ((ach ^ (arow & 7)) * 8);
  int b1row = 64 + arow;
  const unsigned short* srcB0 = kb + (size_t)arow * DMODEL + ((ach ^ (arow & 7)) * 8);
  const unsigned short* srcB1 = kb + (size_t)b1row * DMODEL + ((ach ^ (b1row & 7)) * 8);

  auto stg1 = [&](int boB, int kk) {
    unsigned short* s = (unsigned short*)(sbase + boB);
    gld16(s + tid * 8, srcA + kk);
    gld16(s + 4096 + tid * 8, srcB0 + kk);
    gld16(s + 8192 + tid * 8, srcB1 + kk);
  };

  // ---- GEMM1: S[64 tok][128 e], K=1024, BK=64, 2-phase dbuf
  f32x4 acc[2][2] = {};
  stg1(0, 0);
  __syncthreads();
  for (int t = 0; t < 16; ++t) {
    int curB = (t & 1) * 24576;
    if (t < 15) stg1(((t + 1) & 1) * 24576, (t + 1) * 64);
    bf16x8 aF[2][2], bF[2][2];
#pragma unroll
    for (int ks = 0; ks < 2; ++ks) {
#pragma unroll
      for (int m = 0; m < 2; ++m) {
        int r = wr * 32 + m * 16 + cc;
        aF[ks][m] = *reinterpret_cast<const bf16x8*>(
            sbase + curB + r * 128 + (((ks * 4 + grp) ^ (r & 7)) * 16));
      }
#pragma unroll
      for (int n = 0; n < 2; ++n) {
        int r = wc * 32 + n * 16 + cc;
        bF[ks][n] = *reinterpret_cast<const bf16x8*>(
            sbase + curB + 8192 + r * 128 + (((ks * 4 + grp) ^ (r & 7)) * 16));
      }
    }
#pragma unroll
    for (int ks = 0; ks < 2; ++ks)
#pragma unroll
      for (int m = 0; m < 2; ++m)
#pragma unroll
        for (int n = 0; n < 2; ++n)
          acc[m][n] = __builtin_amdgcn_mfma_f32_16x16x32_bf16(aF[ks][m], bF[ks][n], acc[m][n], 0, 0, 0);
    __syncthreads();
  }

  // ---- V staging bases (256B rows -> 16 chunks, swz mask row&15)
  int v0row = tid >> 4, vch = tid & 15;
  int v1row = 32 + v0row;
  const unsigned short* srcV0 = vb + (size_t)v0row * ESIZE + ((vch ^ (v0row & 15)) * 8);
  const unsigned short* srcV1 = vb + (size_t)v1row * ESIZE + ((vch ^ (v1row & 15)) * 8);
  auto stgV = [&](int boB, int ch) {
    unsigned short* s = (unsigned short*)(sbase + boB);
    const size_t co = (size_t)ch * 64 * ESIZE;
    gld16(s + tid * 8, srcV0 + co);
    gld16(s + 4096 + tid * 8, srcV1 + co);
  };

  stgV(0, 0);  // overlap chunk-0 V load with the relu/lS phase

  // relu*gate -> lS
#pragma unroll
  for (int m = 0; m < 2; ++m) {
    int trow = wr * 32 + m * 16 + grp * 4;
#pragma unroll
    for (int n = 0; n < 2; ++n) {
      int e = wc * 32 + n * 16 + cc;
#pragma unroll
      for (int r = 0; r < 4; ++r) {
        float s = acc[m][n][r];
        s = s > 0.0f ? s * sGate[trow + r] : 0.0f;
        lS[(trow + r) * 136 + e] = f2bf(s);
      }
    }
  }
  __syncthreads();  // lS visible + V chunk0 staged

  // S-frags (held in registers across all chunks)
  bf16x8 sF[2][4];
#pragma unroll
  for (int m = 0; m < 2; ++m) {
    int r = wr * 32 + m * 16 + cc;
#pragma unroll
    for (int ks = 0; ks < 4; ++ks)
      sF[m][ks] = *reinterpret_cast<const bf16x8*>((const char*)lS + r * 272 + ks * 64 + grp * 16);
  }
  unsigned short* rB[2][4];
#pragma unroll
  for (int m = 0; m < 2; ++m)
#pragma unroll
    for (int r = 0; r < 4; ++r)
      rB[m][r] = part + (size_t)sRow[wr * 32 + m * 16 + grp * 4 + r] * DMODEL + wc * 16 + cc;

  // ---- GEMM2: out[64 tok][1024 v], 16 chunks of 64 v-cols, 2-phase dbuf
  for (int ch = 0; ch < 16; ++ch) {
    int curB = (ch & 1) * 16384;
    if (ch < 15) stgV(((ch + 1) & 1) * 16384, ch + 1);
    int r = wc * 16 + cc;
    bf16x8 vF[4];
#pragma unroll
    for (int ks = 0; ks < 4; ++ks)
      vF[ks] = *reinterpret_cast<const bf16x8*>(
          sbase + curB + r * 256 + (((ks * 4 + grp) ^ cc) * 16));
    f32x4 o[2] = {};
#pragma unroll
    for (int ks = 0; ks < 4; ++ks)
#pragma unroll
      for (int m = 0; m < 2; ++m)
        o[m] = __builtin_amdgcn_mfma_f32_16x16x32_bf16(sF[m][ks], vF[ks], o[m], 0, 0, 0);
#pragma unroll
    for (int m = 0; m < 2; ++m)
#pragma unroll
      for (int r2 = 0; r2 < 4; ++r2)
        rB[m][r2][ch * 64] = f2bf(o[m][r2]);
    __syncthreads();
  }
}

// K7: out[n][v] = sum_h part[h*N_TOK+n][v]  (bf16 partials -> fp32 out, full overwrite)
__global__ void k_sum(const unsigned short* __restrict__ part, float* __restrict__ out) {
  size_t i = ((size_t)blockIdx.x * 256 + threadIdx.x) * 8;
  const size_t stride = (size_t)N_TOK * DMODEL;
  uint4 a = *reinterpret_cast<const uint4*>(part + i);
  uint4 b = *reinterpret_cast<const uint4*>(part + stride + i);
  uint4 c = *reinterpret_cast<const uint4*>(part + 2 * stride + i);
  uint4 d = *reinterpret_cast<const uint4*>(part + 3 * stride + i);
  float o[8];
#pragma unroll
  for (int q = 0; q < 4; ++q) {
    unsigned ua = (&a.x)[q], ub = (&b.x)[q], uc = (&c.x)[q], ud = (&d.x)[q];
    o[q * 2 + 0] = b2f((unsigned short)ua) + b2f((unsigned short)ub) +
                   b2f((unsigned short)uc) + b2f((unsigned short)ud);
    o[q * 2 + 1] = b2f((unsigned short)(ua >> 16)) + b2f((unsigned short)(ub >> 16)) +
                   b2f((unsigned short)(uc >> 16)) + b2f((unsigned short)(ud >> 16));
  }
  *reinterpret_cast<float4*>(out + i) = make_float4(o[0], o[1], o[2], o[3]);
  *reinterpret_cast<float4*>(out + i + 4) = make_float4(o[4], o[5], o[6], o[7]);
}

extern "C" void kernel_launch(void* const* d_in, const int* in_sizes, int n_in,
                              void* d_out, int out_size, void* d_ws, size_t ws_size,
                              hipStream_t stream) {
  const float* x = (const float*)d_in[0];
  const float* esel = (const float*)d_in[1];
  const float* keys = (const float*)d_in[2];
  const float* values = (const float*)d_in[3];
  float* out = (float*)d_out;

  char* p = (char*)d_ws;
  unsigned short* xbf = (unsigned short*)p; p += (size_t)N_TOK * DMODEL * 2;
  unsigned short* kbf = (unsigned short*)p; p += (size_t)NEXP * DMODEL * ESIZE * 2;
  unsigned short* vbf = (unsigned short*)p; p += (size_t)NEXP * DMODEL * ESIZE * 2;
  float* selT = (float*)p; p += (size_t)DMODEL * NEXP * 4;
  float4* g4 = (float4*)p; p += (size_t)N_TOK * 16;
  int4* idx4 = (int4*)p; p += (size_t)N_TOK * 16;
  int* btok = (int*)p; p += (size_t)NEXP * N_TOK * 4;
  float* bgate = (float*)p; p += (size_t)NEXP * N_TOK * 4;
  unsigned short* part = (unsigned short*)p;
  p += ((size_t)4 * N_TOK + WL_MAX) * DMODEL * 2;  // + per-block dump rows
  int* cnt = (int*)p; p += 256;
  int* wl = (int*)p; p += WL_MAX * 4;
  (void)ws_size; (void)in_sizes; (void)n_in;

  hipMemsetAsync(cnt, 0, 64 * sizeof(int), stream);
  k_selT<<<256, 256, 0, stream>>>(esel, selT);
  k_transpose<<<dim3(128, 64), 256, 0, stream>>>(keys, kbf, DMODEL, ESIZE);
  k_transpose<<<dim3(128, 64), 256, 0, stream>>>(values, vbf, ESIZE, DMODEL);
  k_router<<<256, 256, 0, stream>>>(x, selT, xbf, idx4, g4);
  k_bucket<<<32, 256, 0, stream>>>(idx4, g4, btok, bgate, cnt);
  k_worklist<<<1, 64, 0, stream>>>(cnt, wl);
  k_expert<<<WL_MAX, 512, 0, stream>>>(xbf, kbf, vbf, wl, btok, bgate, cnt, part);
  k_sum<<<(N_TOK * DMODEL / 8) / 256, 256, 0, stream>>>(part, out);
}

// Round 8
// 171.279 us; speedup vs baseline: 1.7085x; 1.0144x over previous
//
#include <hip/hip_runtime.h>

typedef __bf16 bf16x8 __attribute__((ext_vector_type(8)));
typedef float f32x4 __attribute__((ext_vector_type(4)));

#define N_TOK 8192
#define DMODEL 1024
#define NEXP 64
#define ESIZE 128
#define WL_MAX 576   // sum ceil(ck/64) <= 32768/64 + 64 = 576 (divisible by 8)

__device__ __forceinline__ unsigned short f2bf(float f) {
  unsigned int u = __builtin_bit_cast(unsigned int, f);
  u += 0x7FFFu + ((u >> 16) & 1u);
  return (unsigned short)(u >> 16);
}

__device__ __forceinline__ float b2f(unsigned short u) {
  unsigned int v = ((unsigned int)u) << 16;
  return __builtin_bit_cast(float, v);
}

// async global->LDS, 16B per lane. LDS dest lane-linear within the wave.
__device__ __forceinline__ void gld16(unsigned short* lds, const unsigned short* g) {
  __builtin_amdgcn_global_load_lds(
      (const __attribute__((address_space(1))) unsigned int*)g,
      (__attribute__((address_space(3))) unsigned int*)lds, 16, 0, 0);
}

// K0: expert_sel [64][1024] -> selT [1024][64] fp32
__global__ void k_selT(const float* __restrict__ in, float* __restrict__ outT) {
  int id = blockIdx.x * 256 + threadIdx.x;
  int e = id & 63, j = id >> 6;
  outT[id] = in[e * DMODEL + j];
}

// K2: per-expert transpose+cast: in [B][R][C] f32 -> out [B][C][R] bf16
__global__ void k_transpose(const float* __restrict__ in, unsigned short* __restrict__ out,
                            int R, int C) {
  __shared__ float t[32][33];
  int b = blockIdx.y;
  int tilesC = C >> 5;
  int tr = blockIdx.x / tilesC, tc = blockIdx.x % tilesC;
  int lr = threadIdx.x >> 5, lc = threadIdx.x & 31;
  const float* ip = in + (size_t)b * R * C;
  unsigned short* op = out + (size_t)b * R * C;
#pragma unroll
  for (int p = 0; p < 4; ++p)
    t[p * 8 + lr][lc] = ip[(size_t)(tr * 32 + p * 8 + lr) * C + tc * 32 + lc];
  __syncthreads();
#pragma unroll
  for (int p = 0; p < 4; ++p)
    op[(size_t)(tc * 32 + p * 8 + lr) * R + tr * 32 + lc] = f2bf(t[lc][p * 8 + lr]);
}

// K3: router — round-6 structure (LDS-tiled fp64-accum GEMM + serial LDS top-4),
// occupancy-doubled: 16 tokens/block x 512 blocks (2 blocks/CU, 8 waves/CU).
// Thread = (token ty, expert-quad tx). Fused bf16 cast of x. Deterministic:
// fixed ascending-j fp64 FMA chains, serial lowest-index-wins top-4.
__global__ __launch_bounds__(256) void k_router(const float* __restrict__ x,
                                                const float* __restrict__ selT,
                                                unsigned short* __restrict__ xbf,
                                                int4* __restrict__ idx4,
                                                float4* __restrict__ g4) {
  int tid = threadIdx.x;
  int tok0 = blockIdx.x * 16;
  int ty = tid >> 4, tx = tid & 15;            // ty: token, tx: expert quad
  __shared__ float lx[32][18];                 // [d-in-chunk][tok], pad->72B rows
  __shared__ float ls[32][64];                 // [d][e]
  __shared__ double lg[16][65];                // logits [tok][e]

  int tokr = tid >> 4, dseg = (tid & 15) * 2;  // x staging map (2 floats/thread)
  int srow = tid >> 3, scol = (tid & 7) * 8;   // sel staging map (8 floats/thread)

  double a0 = 0.0, a1 = 0.0, a2 = 0.0, a3 = 0.0;

  for (int cc = 0; cc < DMODEL; cc += 32) {
    float2 xv = *reinterpret_cast<const float2*>(&x[(size_t)(tok0 + tokr) * DMODEL + cc + dseg]);
    lx[dseg + 0][tokr] = xv.x;
    lx[dseg + 1][tokr] = xv.y;
    // fused bf16 cast-out of x (each element written exactly once)
    unsigned pk = f2bf(xv.x) | ((unsigned)f2bf(xv.y) << 16);
    *reinterpret_cast<unsigned*>(&xbf[(size_t)(tok0 + tokr) * DMODEL + cc + dseg]) = pk;
    *reinterpret_cast<float4*>(&ls[srow][scol]) =
        *reinterpret_cast<const float4*>(&selT[(size_t)(cc + srow) * 64 + scol]);
    *reinterpret_cast<float4*>(&ls[srow][scol + 4]) =
        *reinterpret_cast<const float4*>(&selT[(size_t)(cc + srow) * 64 + scol + 4]);
    __syncthreads();
#pragma unroll
    for (int j = 0; j < 32; ++j) {
      double xd = (double)lx[j][ty];
      float4 sj = *reinterpret_cast<const float4*>(&ls[j][tx * 4]);
      a0 += xd * (double)sj.x;
      a1 += xd * (double)sj.y;
      a2 += xd * (double)sj.z;
      a3 += xd * (double)sj.w;
    }
    __syncthreads();
  }

  lg[ty][tx * 4 + 0] = a0;
  lg[ty][tx * 4 + 1] = a1;
  lg[ty][tx * 4 + 2] = a2;
  lg[ty][tx * 4 + 3] = a3;
  __syncthreads();

  if (tid < 16) {
    double bv0 = -1.0e300, bv1 = -1.0e300, bv2 = -1.0e300, bv3 = -1.0e300;
    int bi0 = 0, bi1 = 0, bi2 = 0, bi3 = 0;
    for (int e = 0; e < 64; ++e) {
      double v = lg[tid][e];
      if (v > bv3) {
        if (v > bv0) {
          bv3 = bv2; bi3 = bi2; bv2 = bv1; bi2 = bi1; bv1 = bv0; bi1 = bi0; bv0 = v; bi0 = e;
        } else if (v > bv1) {
          bv3 = bv2; bi3 = bi2; bv2 = bv1; bi2 = bi1; bv1 = v; bi1 = e;
        } else if (v > bv2) {
          bv3 = bv2; bi3 = bi2; bv2 = v; bi2 = e;
        } else {
          bv3 = v; bi3 = e;
        }
      }
    }
    idx4[tok0 + tid] = make_int4(bi0, bi1, bi2, bi3);
    float4 g;
    g.x = 1.0f / (1.0f + __expf(-(float)bv0));
    g.y = 1.0f / (1.0f + __expf(-(float)bv1));
    g.z = 1.0f / (1.0f + __expf(-(float)bv2));
    g.w = 1.0f / (1.0f + __expf(-(float)bv3));
    g4[tok0 + tid] = g;
  }
}

// K4: two-level atomic bucketize (slot order non-deterministic; output invariant).
__global__ __launch_bounds__(256) void k_bucket(const int4* __restrict__ idx4,
                                                const float4* __restrict__ g4,
                                                int* __restrict__ btok,
                                                float* __restrict__ bgate,
                                                int* __restrict__ cnt) {
  __shared__ int lcnt[64];
  __shared__ int lbase[64];
  int tid = threadIdx.x;
  if (tid < 64) lcnt[tid] = 0;
  __syncthreads();
  int n = blockIdx.x * 256 + tid;
  int4 I = idx4[n];
  float4 G = g4[n];
  int e[4] = {I.x, I.y, I.z, I.w};
  float g[4] = {G.x, G.y, G.z, G.w};
  int pos[4];
#pragma unroll
  for (int h = 0; h < 4; ++h) pos[h] = atomicAdd(&lcnt[e[h]], 1);
  __syncthreads();
  if (tid < 64 && lcnt[tid] > 0) lbase[tid] = atomicAdd(&cnt[tid], lcnt[tid]);
  __syncthreads();
#pragma unroll
  for (int h = 0; h < 4; ++h) {
    int slot = lbase[e[h]] + pos[h];
    btok[e[h] * N_TOK + slot] = h * N_TOK + n;
    bgate[e[h] * N_TOK + slot] = g[h];
  }
}

// K5: compact worklist of (expert, tile64) pairs. 1 block, 64 threads.
__global__ void k_worklist(const int* __restrict__ cnt, int* __restrict__ wl) {
  int lane = threadIdx.x;
  int nt = (cnt[lane] + 63) >> 6;
  int off = nt;
  for (int d = 1; d < 64; d <<= 1) {
    int o = __shfl_up(off, d);
    if (lane >= d) off += o;
  }
  int total = __shfl(off, 63);
  off -= nt;
  for (int t = 0; t < nt; ++t) wl[off + t] = (lane << 8) | t;
  for (int i = total + lane; i < WL_MAX; i += 64) wl[i] = -1;
}

// K6: fused per-(expert,tile64). global_load_lds bulk staging with DOUBLE-BUFFERED
// 2-phase prefetch. 512 threads = 8 waves. LDS 65.5KB -> 2 blocks/CU.
__global__ __launch_bounds__(512, 4) void k_expert(
    const unsigned short* __restrict__ xbf, const unsigned short* __restrict__ kbf,
    const unsigned short* __restrict__ vbf, const int* __restrict__ wl,
    const int* __restrict__ btok, const float* __restrict__ bgate,
    const int* __restrict__ cnt, unsigned short* __restrict__ part) {
  int wid = (blockIdx.x & 7) * (WL_MAX / 8) + (blockIdx.x >> 3);
  int wle = wl[wid];
  if (wle < 0) return;
  int k = wle >> 8, tile = wle & 255;
  int ck = cnt[k];
  int tid = threadIdx.x, lane = tid & 63;
  int wv = tid >> 6, wr = wv >> 2, wc = wv & 3;
  int cc = lane & 15, grp = lane >> 4;

  __shared__ alignas(16) unsigned short stage[24576];  // 48 KB: 2 x (A 8KB + B 16KB)
  __shared__ alignas(16) unsigned short lS[64 * 136];  // 17.4 KB scores
  __shared__ int sRow[64];
  __shared__ float sGate[64];

  if (tid < 64) {
    int i = tile * 64 + tid;
    bool valid = i < ck;
    sRow[tid] = valid ? btok[k * N_TOK + i] : 4 * N_TOK + wid;  // per-block dump row
    sGate[tid] = valid ? bgate[k * N_TOK + i] : 0.0f;
  }
  __syncthreads();

  const unsigned short* kb = kbf + (size_t)k * (ESIZE * DMODEL);
  const unsigned short* vb = vbf + (size_t)k * (DMODEL * ESIZE);
  char* sbase = (char*)stage;

  // ---- GEMM1 staging bases (src chunk = phys ^ (row&7), LDS dest lane-linear)
  int arow = tid >> 3, ach = tid & 7;
  const unsigned short* srcA =
      xbf + (size_t)(sRow[arow] & (N_TOK - 1)) * DMODEL + ((ach ^ (arow & 7)) * 8);
  int b1row = 64 + arow;
  const unsigned short* srcB0 = kb + (size_t)arow * DMODEL + ((ach ^ (arow & 7)) * 8);
  const unsigned short* srcB1 = kb + (size_t)b1row * DMODEL + ((ach ^ (b1row & 7)) * 8);

  auto stg1 = [&](int boB, int kk) {
    unsigned short* s = (unsigned short*)(sbase + boB);
    gld16(s + tid * 8, srcA + kk);
    gld16(s + 4096 + tid * 8, srcB0 + kk);
    gld16(s + 8192 + tid * 8, srcB1 + kk);
  };

  // ---- GEMM1: S[64 tok][128 e], K=1024, BK=64, 2-phase dbuf
  f32x4 acc[2][2] = {};
  stg1(0, 0);
  __syncthreads();
  for (int t = 0; t < 16; ++t) {
    int curB = (t & 1) * 24576;
    if (t < 15) stg1(((t + 1) & 1) * 24576, (t + 1) * 64);
    bf16x8 aF[2][2], bF[2][2];
#pragma unroll
    for (int ks = 0; ks < 2; ++ks) {
#pragma unroll
      for (int m = 0; m < 2; ++m) {
        int r = wr * 32 + m * 16 + cc;
        aF[ks][m] = *reinterpret_cast<const bf16x8*>(
            sbase + curB + r * 128 + (((ks * 4 + grp) ^ (r & 7)) * 16));
      }
#pragma unroll
      for (int n = 0; n < 2; ++n) {
        int r = wc * 32 + n * 16 + cc;
        bF[ks][n] = *reinterpret_cast<const bf16x8*>(
            sbase + curB + 8192 + r * 128 + (((ks * 4 + grp) ^ (r & 7)) * 16));
      }
    }
#pragma unroll
    for (int ks = 0; ks < 2; ++ks)
#pragma unroll
      for (int m = 0; m < 2; ++m)
#pragma unroll
        for (int n = 0; n < 2; ++n)
          acc[m][n] = __builtin_amdgcn_mfma_f32_16x16x32_bf16(aF[ks][m], bF[ks][n], acc[m][n], 0, 0, 0);
    __syncthreads();
  }

  // ---- V staging bases (256B rows -> 16 chunks, swz mask row&15)
  int v0row = tid >> 4, vch = tid & 15;
  int v1row = 32 + v0row;
  const unsigned short* srcV0 = vb + (size_t)v0row * ESIZE + ((vch ^ (v0row & 15)) * 8);
  const unsigned short* srcV1 = vb + (size_t)v1row * ESIZE + ((vch ^ (v1row & 15)) * 8);
  auto stgV = [&](int boB, int ch) {
    unsigned short* s = (unsigned short*)(sbase + boB);
    const size_t co = (size_t)ch * 64 * ESIZE;
    gld16(s + tid * 8, srcV0 + co);
    gld16(s + 4096 + tid * 8, srcV1 + co);
  };

  stgV(0, 0);  // overlap chunk-0 V load with the relu/lS phase

  // relu*gate -> lS
#pragma unroll
  for (int m = 0; m < 2; ++m) {
    int trow = wr * 32 + m * 16 + grp * 4;
#pragma unroll
    for (int n = 0; n < 2; ++n) {
      int e = wc * 32 + n * 16 + cc;
#pragma unroll
      for (int r = 0; r < 4; ++r) {
        float s = acc[m][n][r];
        s = s > 0.0f ? s * sGate[trow + r] : 0.0f;
        lS[(trow + r) * 136 + e] = f2bf(s);
      }
    }
  }
  __syncthreads();  // lS visible + V chunk0 staged

  // S-frags (held in registers across all chunks)
  bf16x8 sF[2][4];
#pragma unroll
  for (int m = 0; m < 2; ++m) {
    int r = wr * 32 + m * 16 + cc;
#pragma unroll
    for (int ks = 0; ks < 4; ++ks)
      sF[m][ks] = *reinterpret_cast<const bf16x8*>((const char*)lS + r * 272 + ks * 64 + grp * 16);
  }
  unsigned short* rB[2][4];
#pragma unroll
  for (int m = 0; m < 2; ++m)
#pragma unroll
    for (int r = 0; r < 4; ++r)
      rB[m][r] = part + (size_t)sRow[wr * 32 + m * 16 + grp * 4 + r] * DMODEL + wc * 16 + cc;

  // ---- GEMM2: out[64 tok][1024 v], 16 chunks of 64 v-cols, 2-phase dbuf
  for (int ch = 0; ch < 16; ++ch) {
    int curB = (ch & 1) * 16384;
    if (ch < 15) stgV(((ch + 1) & 1) * 16384, ch + 1);
    int r = wc * 16 + cc;
    bf16x8 vF[4];
#pragma unroll
    for (int ks = 0; ks < 4; ++ks)
      vF[ks] = *reinterpret_cast<const bf16x8*>(
          sbase + curB + r * 256 + (((ks * 4 + grp) ^ cc) * 16));
    f32x4 o[2] = {};
#pragma unroll
    for (int ks = 0; ks < 4; ++ks)
#pragma unroll
      for (int m = 0; m < 2; ++m)
        o[m] = __builtin_amdgcn_mfma_f32_16x16x32_bf16(sF[m][ks], vF[ks], o[m], 0, 0, 0);
#pragma unroll
    for (int m = 0; m < 2; ++m)
#pragma unroll
      for (int r2 = 0; r2 < 4; ++r2)
        rB[m][r2][ch * 64] = f2bf(o[m][r2]);
    __syncthreads();
  }
}

// K7: out[n][v] = sum_h part[h*N_TOK+n][v]  (bf16 partials -> fp32 out, full overwrite)
__global__ void k_sum(const unsigned short* __restrict__ part, float* __restrict__ out) {
  size_t i = ((size_t)blockIdx.x * 256 + threadIdx.x) * 8;
  const size_t stride = (size_t)N_TOK * DMODEL;
  uint4 a = *reinterpret_cast<const uint4*>(part + i);
  uint4 b = *reinterpret_cast<const uint4*>(part + stride + i);
  uint4 c = *reinterpret_cast<const uint4*>(part + 2 * stride + i);
  uint4 d = *reinterpret_cast<const uint4*>(part + 3 * stride + i);
  float o[8];
#pragma unroll
  for (int q = 0; q < 4; ++q) {
    unsigned ua = (&a.x)[q], ub = (&b.x)[q], uc = (&c.x)[q], ud = (&d.x)[q];
    o[q * 2 + 0] = b2f((unsigned short)ua) + b2f((unsigned short)ub) +
                   b2f((unsigned short)uc) + b2f((unsigned short)ud);
    o[q * 2 + 1] = b2f((unsigned short)(ua >> 16)) + b2f((unsigned short)(ub >> 16)) +
                   b2f((unsigned short)(uc >> 16)) + b2f((unsigned short)(ud >> 16));
  }
  *reinterpret_cast<float4*>(out + i) = make_float4(o[0], o[1], o[2], o[3]);
  *reinterpret_cast<float4*>(out + i + 4) = make_float4(o[4], o[5], o[6], o[7]);
}

extern "C" void kernel_launch(void* const* d_in, const int* in_sizes, int n_in,
                              void* d_out, int out_size, void* d_ws, size_t ws_size,
                              hipStream_t stream) {
  const float* x = (const float*)d_in[0];
  const float* esel = (const float*)d_in[1];
  const float* keys = (const float*)d_in[2];
  const float* values = (const float*)d_in[3];
  float* out = (float*)d_out;

  char* p = (char*)d_ws;
  unsigned short* xbf = (unsigned short*)p; p += (size_t)N_TOK * DMODEL * 2;
  unsigned short* kbf = (unsigned short*)p; p += (size_t)NEXP * DMODEL * ESIZE * 2;
  unsigned short* vbf = (unsigned short*)p; p += (size_t)NEXP * DMODEL * ESIZE * 2;
  float* selT = (float*)p; p += (size_t)DMODEL * NEXP * 4;
  float4* g4 = (float4*)p; p += (size_t)N_TOK * 16;
  int4* idx4 = (int4*)p; p += (size_t)N_TOK * 16;
  int* btok = (int*)p; p += (size_t)NEXP * N_TOK * 4;
  float* bgate = (float*)p; p += (size_t)NEXP * N_TOK * 4;
  unsigned short* part = (unsigned short*)p;
  p += ((size_t)4 * N_TOK + WL_MAX) * DMODEL * 2;  // + per-block dump rows
  int* cnt = (int*)p; p += 256;
  int* wl = (int*)p; p += WL_MAX * 4;
  (void)ws_size; (void)in_sizes; (void)n_in;

  hipMemsetAsync(cnt, 0, 64 * sizeof(int), stream);
  k_selT<<<256, 256, 0, stream>>>(esel, selT);
  k_transpose<<<dim3(128, 64), 256, 0, stream>>>(keys, kbf, DMODEL, ESIZE);
  k_transpose<<<dim3(128, 64), 256, 0, stream>>>(values, vbf, ESIZE, DMODEL);
  k_router<<<512, 256, 0, stream>>>(x, selT, xbf, idx4, g4);
  k_bucket<<<32, 256, 0, stream>>>(idx4, g4, btok, bgate, cnt);
  k_worklist<<<1, 64, 0, stream>>>(cnt, wl);
  k_expert<<<WL_MAX, 512, 0, stream>>>(xbf, kbf, vbf, wl, btok, bgate, cnt, part);
  k_sum<<<(N_TOK * DMODEL / 8) / 256, 256, 0, stream>>>(part, out);
}